// Round 3
// baseline (654.007 us; speedup 1.0000x reference)
//
#include <hip/hip_runtime.h>

#define B_SZ 32
#define LK   4096
#define H    512
#define MT   64           // key rows per block
#define NK8  64           // H/8 k-octets
#define AST  1040         // LDS byte stride per k8: 64*16 + 16 pad

typedef __bf16 bf16x8 __attribute__((ext_vector_type(8)));
typedef float  f32x4  __attribute__((ext_vector_type(4)));

__device__ inline unsigned short f2bf_rne(float f) {
    unsigned int u = __float_as_uint(f);
    u += 0x7FFFu + ((u >> 16) & 1u);
    return (unsigned short)(u >> 16);
}
__device__ inline unsigned pack_trunc(float lo, float hi) {
    return __builtin_amdgcn_perm(__float_as_uint(hi), __float_as_uint(lo), 0x07060302u);
}
__device__ inline float tanh_fast(float x) {
    float e = __expf(2.0f * x);
    return 1.0f - 2.0f / (e + 1.0f);
}

// ---- kernel 1: Ua_w fp32 [n][k] -> bf16 k-major tiles ua_t[k8][n][8] ----
__global__ void cvt_ua_kernel(const float* __restrict__ Ua_w, unsigned short* __restrict__ ua_t) {
    int n = blockIdx.x;          // 512 blocks
    int t = threadIdx.x;         // 256 threads, each 2 k's
    float2 f = *(const float2*)(Ua_w + n * H + t * 2);
    unsigned w = (unsigned)f2bf_rne(f.x) | ((unsigned)f2bf_rne(f.y) << 16);
    int k8 = t >> 2, off = t & 3;
    *(unsigned*)(ua_t + (size_t)k8 * (H * 8) + n * 8 + off * 2) = w;
}

// ---- kernel 2: qadd[b][n] = query[b] . Wa_w[n] + Wa_b[n] + Ua_b[n] ----
// grid 256 = 32 b x 8 h-segments of 64; each wave handles 16 h's
__global__ void qproj_kernel(const float* __restrict__ query, const float* __restrict__ Wa_w,
                             const float* __restrict__ Wa_b, const float* __restrict__ Ua_b,
                             float* __restrict__ qadd) {
    __shared__ float qs[H];
    int b = blockIdx.x >> 3;
    int hseg = (blockIdx.x & 7) * 64;
    int t = threadIdx.x, wave = t >> 6, lane = t & 63;
    qs[t] = query[b * H + t];
    qs[t + 256] = query[b * H + t + 256];
    __syncthreads();
    for (int i = 0; i < 16; ++i) {
        int h = hseg + wave * 16 + i;
        const float* wr = Wa_w + (size_t)h * H + lane * 8;
        float4 a = *(const float4*)wr;
        float4 c = *(const float4*)(wr + 4);
        const float* q8 = qs + lane * 8;
        float s = a.x * q8[0] + a.y * q8[1] + a.z * q8[2] + a.w * q8[3]
                + c.x * q8[4] + c.y * q8[5] + c.z * q8[6] + c.w * q8[7];
        s += __shfl_xor(s, 1);  s += __shfl_xor(s, 2);  s += __shfl_xor(s, 4);
        s += __shfl_xor(s, 8);  s += __shfl_xor(s, 16); s += __shfl_xor(s, 32);
        if (lane == 0) qadd[b * H + h] = s + Wa_b[h] + Ua_b[h];
    }
}

// ---- kernel 3: main fused kernel ----
// grid 2048 = 32 b x 64 row-tiles of 64; 256 threads (4 waves)
// keys tile (64x512) staged once in LDS as bf16; n processed in 2 chunks of 256
__global__ __launch_bounds__(256, 2)
void main_kernel(const float* __restrict__ keys, const unsigned short* __restrict__ ua_t,
                 const float* __restrict__ qadd, const float* __restrict__ va_w,
                 const float* __restrict__ va_b, const float* __restrict__ temp,
                 const int* __restrict__ valid, float* __restrict__ p_out,
                 float* __restrict__ pc_part, float* __restrict__ psum_part) {
    __shared__ __align__(16) unsigned char alds[NK8 * AST];  // 66560 B
    __shared__ float swave[4][MT];                           // 1 KB
    __shared__ float pbuf[MT];
    __shared__ float red[4][H];                              // 8 KB

    const int blk  = blockIdx.x;
    const int b    = blk >> 6;
    const int m0   = (blk & 63) * MT;
    const int t    = threadIdx.x;
    const int wave = t >> 6;
    const int lane = t & 63;
    const int lrow = lane & 15;
    const int lquad = lane >> 4;

    const float* keys_b = keys + ((size_t)b * LK + m0) * H;

    // ---- stage: 64 rows x 512 k fp32 -> bf16 LDS [k8][row][8] (trunc pack) ----
    #pragma unroll
    for (int it = 0; it < 16; ++it) {
        int i = it * 256 + t;        // 0..4095
        int k8 = i & 63, row = i >> 6;
        const float* src = keys_b + row * H + k8 * 8;
        float4 f0 = *(const float4*)src;
        float4 f1 = *(const float4*)(src + 4);
        uint4 w;
        w.x = pack_trunc(f0.x, f0.y);
        w.y = pack_trunc(f0.z, f0.w);
        w.z = pack_trunc(f1.x, f1.y);
        w.w = pack_trunc(f1.z, f1.w);
        *(uint4*)(alds + k8 * AST + row * 16) = w;
    }
    __syncthreads();

    // ---- 2 n-chunks of 256; wave n-slice = ch*256 + wave*64 ----
    for (int ch = 0; ch < 2; ++ch) {
        const int nb = ch * 256 + wave * 64;

        float va[4], qa[4];
        #pragma unroll
        for (int nt = 0; nt < 4; ++nt) {
            int n = nb + nt * 16 + lrow;
            va[nt] = va_w[n];
            qa[nt] = qadd[b * H + n];
        }

        f32x4 acc[4][4];
        #pragma unroll
        for (int mt = 0; mt < 4; ++mt)
            #pragma unroll
            for (int nt = 0; nt < 4; ++nt)
                acc[mt][nt] = (f32x4){0.f, 0.f, 0.f, 0.f};

        bf16x8 af[4], bf[4], afn[4], bfn[4];
        {
            int k8g = lquad;
            #pragma unroll
            for (int mt = 0; mt < 4; ++mt)
                af[mt] = *(const bf16x8*)(alds + k8g * AST + (mt * 16 + lrow) * 16);
            #pragma unroll
            for (int nt = 0; nt < 4; ++nt)
                bf[nt] = *(const bf16x8*)(ua_t + (size_t)k8g * (H * 8) + (nb + nt * 16 + lrow) * 8);
        }
        #pragma unroll
        for (int ks = 0; ks < 16; ++ks) {
            if (ks < 15) {
                int k8g = (ks + 1) * 4 + lquad;
                #pragma unroll
                for (int mt = 0; mt < 4; ++mt)
                    afn[mt] = *(const bf16x8*)(alds + k8g * AST + (mt * 16 + lrow) * 16);
                #pragma unroll
                for (int nt = 0; nt < 4; ++nt)
                    bfn[nt] = *(const bf16x8*)(ua_t + (size_t)k8g * (H * 8) + (nb + nt * 16 + lrow) * 8);
            }
            #pragma unroll
            for (int nt = 0; nt < 4; ++nt)
                #pragma unroll
                for (int mt = 0; mt < 4; ++mt)
                    acc[mt][nt] = __builtin_amdgcn_mfma_f32_16x16x32_bf16(af[mt], bf[nt], acc[mt][nt], 0, 0, 0);
            #pragma unroll
            for (int j = 0; j < 4; ++j) { af[j] = afn[j]; bf[j] = bfn[j]; }
        }

        // partial score over this n-chunk
        #pragma unroll
        for (int mt = 0; mt < 4; ++mt) {
            #pragma unroll
            for (int r = 0; r < 4; ++r) {
                float s = 0.f;
                #pragma unroll
                for (int nt = 0; nt < 4; ++nt)
                    s += tanh_fast(acc[mt][nt][r] + qa[nt]) * va[nt];
                s += __shfl_xor(s, 1); s += __shfl_xor(s, 2);
                s += __shfl_xor(s, 4); s += __shfl_xor(s, 8);
                if (lrow == 0) {
                    int row = mt * 16 + lquad * 4 + r;
                    if (ch == 0) swave[wave][row] = s;
                    else         swave[wave][row] += s;
                }
            }
        }
    }
    __syncthreads();

    // ---- p = exp(score/T) masked; per-block psum partial ----
    if (t < MT) {
        float score = (swave[0][t] + swave[1][t] + swave[2][t] + swave[3][t] + va_b[0]) / temp[0];
        int l = m0 + t;
        float p = (l < valid[b]) ? __expf(score) : 0.f;
        p_out[(size_t)b * LK + l] = p;
        pbuf[t] = p;
        float s = p;
        s += __shfl_xor(s, 1); s += __shfl_xor(s, 2); s += __shfl_xor(s, 4);
        s += __shfl_xor(s, 8); s += __shfl_xor(s, 16); s += __shfl_xor(s, 32);
        if (t == 0) psum_part[blk] = s;
    }
    __syncthreads();

    // ---- partial context: pc_part[blk][h] = sum_row p[row]*key_bf[row][h] ----
    {
        int oct = t & 63, rg = t >> 6;     // k-octet x row-group of 16
        float s[8] = {0.f, 0.f, 0.f, 0.f, 0.f, 0.f, 0.f, 0.f};
        #pragma unroll
        for (int rr = 0; rr < 16; ++rr) {
            int row = rg * 16 + rr;
            bf16x8 kv = *(const bf16x8*)(alds + oct * AST + row * 16);
            float pr = pbuf[row];
            #pragma unroll
            for (int j = 0; j < 8; ++j)
                s[j] += pr * (float)kv[j];
        }
        #pragma unroll
        for (int j = 0; j < 8; ++j)
            red[rg][oct * 8 + j] = s[j];
    }
    __syncthreads();
    #pragma unroll
    for (int rep = 0; rep < 2; ++rep) {
        int h = t + rep * 256;
        pc_part[(size_t)blk * H + h] = red[0][h] + red[1][h] + red[2][h] + red[3][h];
    }
}

// ---- kernel 4: finalize ----
// grid 32*18: seg 0..15 -> weights chunks; seg 16,17 -> context halves
__global__ void finalize_kernel(const float* __restrict__ p, const float* __restrict__ pc_part,
                                const float* __restrict__ psum_part, float* __restrict__ out) {
    int b = blockIdx.x / 18;
    int seg = blockIdx.x % 18;
    int t = threadIdx.x;
    __shared__ float tmp;
    if (t < 64) {
        float v = psum_part[b * 64 + t];
        v += __shfl_xor(v, 1);  v += __shfl_xor(v, 2);  v += __shfl_xor(v, 4);
        v += __shfl_xor(v, 8);  v += __shfl_xor(v, 16); v += __shfl_xor(v, 32);
        if (t == 0) tmp = v;
    }
    __syncthreads();
    float inv = 1.0f / tmp;
    if (seg < 16) {
        int l = seg * 256 + t;
        out[B_SZ * H + (size_t)b * LK + l] = p[(size_t)b * LK + l] * inv;
    } else {
        int h = (seg - 16) * 256 + t;
        float s = 0.f;
        #pragma unroll 8
        for (int i = 0; i < 64; ++i)
            s += pc_part[((size_t)b * 64 + i) * H + h];
        out[b * H + h] = s * inv;
    }
}

extern "C" void kernel_launch(void* const* d_in, const int* in_sizes, int n_in,
                              void* d_out, int out_size, void* d_ws, size_t ws_size,
                              hipStream_t stream) {
    const float* query = (const float*)d_in[0];
    const float* keys  = (const float*)d_in[1];
    const float* Wa_w  = (const float*)d_in[2];
    const float* Wa_b  = (const float*)d_in[3];
    const float* Ua_w  = (const float*)d_in[4];
    const float* Ua_b  = (const float*)d_in[5];
    const float* Va_w  = (const float*)d_in[6];
    const float* Va_b  = (const float*)d_in[7];
    const float* temp  = (const float*)d_in[8];
    const int*   valid = (const int*)d_in[9];
    float* out = (float*)d_out;

    char* ws = (char*)d_ws;
    unsigned short* ua_t = (unsigned short*)ws;            //   524288 B
    float* qadd      = (float*)(ws + 524288);              //    65536 B
    float* p         = (float*)(ws + 589824);              //   524288 B
    float* psum_part = (float*)(ws + 1114112);             //     8192 B
    float* pc_part   = (float*)(ws + 1122304);             //  4194304 B  (total ~5.3 MB)

    cvt_ua_kernel<<<H, 256, 0, stream>>>(Ua_w, ua_t);
    qproj_kernel<<<B_SZ * 8, 256, 0, stream>>>(query, Wa_w, Wa_b, Ua_b, qadd);
    main_kernel<<<B_SZ * (LK / MT), 256, 0, stream>>>(keys, ua_t, qadd, Va_w, Va_b,
                                                      temp, valid, p, pc_part, psum_part);
    finalize_kernel<<<B_SZ * 18, 256, 0, stream>>>(p, pc_part, psum_part, out);
}